// Round 1
// baseline (500.493 us; speedup 1.0000x reference)
//
#include <hip/hip_runtime.h>
#include <math.h>

#define N_FRAMES 65536
#define M1 256      // 2*N_MEMORY
#define MEM 128     // N_MEMORY
#define K1 512      // INPUT_LEN
#define M2 256      // OUTPUT_LEN
#define CHUNK 128   // frames per scan chunk
#define G (N_FRAMES/CHUNK)   // 512 chunks

__device__ __forceinline__ float sigm(float x){ return 1.0f/(1.0f+__expf(-x)); }

// ---------------- prep: transpose W1 (256x512 -> 512x256), W2 (256x128 -> 128x256)
__global__ __launch_bounds__(256) void k_prep(const float* __restrict__ W1, const float* __restrict__ W2,
                                              float* __restrict__ W1T, float* __restrict__ W2T){
  int i = blockIdx.x*256 + threadIdx.x;
  if (i < M1*K1){ int m = i / K1, k = i % K1; W1T[k*M1+m] = W1[i]; }
  if (i < M2*MEM){ int m = i / MEM, k = i % MEM; W2T[k*M2+m] = W2[i]; }
}

// ---------------- gemm1 + sigmoid + a,b production
// block: 256 threads, 64 frames. thread owns rows {m0..m0+3, m0+128..m0+131} x 8 frames.
#define TN 64
#define KC 32
__global__ __launch_bounds__(256) void k_gemm1(const float* __restrict__ x, const float* __restrict__ W1T,
        const float* __restrict__ B1, float* __restrict__ Aa, float* __restrict__ Bb){
  __shared__ float ws[KC*M1];    // [kk][r]
  __shared__ float xs[KC*TN];    // [kk][f]
  const int tid = threadIdx.x;
  const int F0 = blockIdx.x * TN;
  const int m0 = (tid >> 3) * 4;        // 0..124
  const int f0 = (tid & 7) * 8;         // 0..56
  float acc[8][8];
  #pragma unroll
  for (int i=0;i<8;i++)
    #pragma unroll
    for (int j=0;j<8;j++) acc[i][j]=0.f;

  for (int k0=0;k0<K1;k0+=KC){
    // stage W1T chunk: KC*M1 = 8192 floats = 2048 float4 (flat contiguous region)
    const float4* wsrc = (const float4*)(W1T + k0*M1);
    float4* wdst = (float4*)ws;
    #pragma unroll
    for (int l=0;l<8;l++) wdst[tid + l*256] = wsrc[tid + l*256];
    // stage x chunk: KC rows x TN frames = 512 float4
    float4* xdst = (float4*)xs;
    #pragma unroll
    for (int l=0;l<2;l++){
      int j = tid + l*256;            // 0..511
      int kk = j >> 4, fi = j & 15;
      xdst[j] = *(const float4*)(x + (size_t)(k0+kk)*N_FRAMES + F0 + fi*4);
    }
    __syncthreads();
    #pragma unroll
    for (int kk=0; kk<KC; ++kk){
      float4 wl = *(const float4*)(ws + kk*M1 + m0);
      float4 wr = *(const float4*)(ws + kk*M1 + m0 + 128);
      float4 x0 = *(const float4*)(xs + kk*TN + f0);
      float4 x1 = *(const float4*)(xs + kk*TN + f0 + 4);
      float wv[8] = {wl.x,wl.y,wl.z,wl.w, wr.x,wr.y,wr.z,wr.w};
      float xv[8] = {x0.x,x0.y,x0.z,x0.w, x1.x,x1.y,x1.z,x1.w};
      #pragma unroll
      for (int i=0;i<8;i++)
        #pragma unroll
        for (int j=0;j<8;j++)
          acc[i][j] = fmaf(wv[i], xv[j], acc[i][j]);
    }
    __syncthreads();
  }
  float4 b1l = *(const float4*)(B1 + m0);
  float4 b1r = *(const float4*)(B1 + m0 + 128);
  float bl[4] = {b1l.x,b1l.y,b1l.z,b1l.w};
  float br[4] = {b1r.x,b1r.y,b1r.z,b1r.w};
  #pragma unroll
  for (int j=0;j<8;j++){
    int t = F0 + f0 + j;
    float a4[4], b4[4];
    #pragma unroll
    for (int i=0;i<4;i++){
      float le = sigm(acc[i][j]   + bl[i]);
      float ri = sigm(acc[4+i][j] + br[i]);
      a4[i] = le*ri;
      b4[i] = 1.0f - le;
    }
    *(float4*)(Aa + (size_t)t*MEM + m0) = make_float4(a4[0],a4[1],a4[2],a4[3]);
    *(float4*)(Bb + (size_t)t*MEM + m0) = make_float4(b4[0],b4[1],b4[2],b4[3]);
  }
}

// ---------------- chunk-local affine composition: (A,B) per chunk per channel
__global__ __launch_bounds__(128) void k_red(const float* __restrict__ Aa, const float* __restrict__ Bb,
                                             float* __restrict__ Ac, float* __restrict__ Bc){
  const int m = threadIdx.x, g = blockIdx.x;
  const float* ap = Aa + (size_t)g*CHUNK*MEM + m;
  const float* bp = Bb + (size_t)g*CHUNK*MEM + m;
  float A = 1.f, B = 0.f;
  #pragma unroll 8
  for (int t=0;t<CHUNK;t++){
    float a = ap[(size_t)t*MEM], b = bp[(size_t)t*MEM];
    B = fmaf(a, B, b);
    A *= a;
  }
  Ac[g*MEM+m] = A;
  Bc[g*MEM+m] = B;
}

// ---------------- exclusive scan of chunk aggregates: Pb[g] = s_{g*CHUNK-1}
__global__ __launch_bounds__(128) void k_scan(const float* __restrict__ Ac, const float* __restrict__ Bc,
                                              float* __restrict__ Pb){
  const int m = threadIdx.x;
  float B = 0.f;
  #pragma unroll 8
  for (int g=0; g<G; ++g){
    Pb[g*MEM+m] = B;
    B = fmaf(Ac[g*MEM+m], B, Bc[g*MEM+m]);
  }
}

// ---------------- apply prefix (recompute z into LDS) + fused GEMM2 + epilogue
#define ZP 132     // padded z row stride (floats): 16B-aligned rows, odd-ish banking
#define KC2 32
__global__ __launch_bounds__(512) void k_apply(const float* __restrict__ Aa, const float* __restrict__ Bb,
        const float* __restrict__ Pb, const float* __restrict__ W2T, const float* __restrict__ B2,
        float* __restrict__ out){
  __shared__ float zs[MEM*ZP];     // [m][t]
  __shared__ float w2s[KC2*M2];    // [kk][r]
  const int tid = threadIdx.x;
  const int g = blockIdx.x;
  const int T0 = g*CHUNK;

  if (tid < MEM){
    const int m = tid;
    float s = Pb[g*MEM+m];         // s_{T0-1}
    const float* ap = Aa + (size_t)T0*MEM + m;
    const float* bp = Bb + (size_t)T0*MEM + m;
    #pragma unroll 4
    for (int t=0;t<CHUNK;t+=4){
      float z0 = s; s = fmaf(ap[(t+0)*MEM], s, bp[(t+0)*MEM]);
      float z1 = s; s = fmaf(ap[(t+1)*MEM], s, bp[(t+1)*MEM]);
      float z2 = s; s = fmaf(ap[(t+2)*MEM], s, bp[(t+2)*MEM]);
      float z3 = s; s = fmaf(ap[(t+3)*MEM], s, bp[(t+3)*MEM]);
      *(float4*)(zs + m*ZP + t) = make_float4(z0,z1,z2,z3);
    }
  }
  __syncthreads();

  const int r0 = (tid >> 4) * 8;        // 0..248
  const int f0 = (tid & 15) * 8;        // 0..120
  float acc[8][8];
  #pragma unroll
  for (int i=0;i<8;i++)
    #pragma unroll
    for (int j=0;j<8;j++) acc[i][j]=0.f;

  for (int k0=0;k0<MEM;k0+=KC2){
    const float4* wsrc = (const float4*)(W2T + k0*M2);
    float4* wdst = (float4*)w2s;
    #pragma unroll
    for (int l=0;l<4;l++) wdst[tid + l*512] = wsrc[tid + l*512];
    __syncthreads();
    #pragma unroll
    for (int kk=0;kk<KC2;++kk){
      float4 w0 = *(const float4*)(w2s + kk*M2 + r0);
      float4 w1 = *(const float4*)(w2s + kk*M2 + r0 + 4);
      float4 z0 = *(const float4*)(zs + (k0+kk)*ZP + f0);
      float4 z1 = *(const float4*)(zs + (k0+kk)*ZP + f0 + 4);
      float wv[8] = {w0.x,w0.y,w0.z,w0.w, w1.x,w1.y,w1.z,w1.w};
      float zv[8] = {z0.x,z0.y,z0.z,z0.w, z1.x,z1.y,z1.z,z1.w};
      #pragma unroll
      for (int i=0;i<8;i++)
        #pragma unroll
        for (int j=0;j<8;j++)
          acc[i][j] = fmaf(wv[i], zv[j], acc[i][j]);
    }
    __syncthreads();
  }

  float4 b2a = *(const float4*)(B2 + r0);
  float4 b2b = *(const float4*)(B2 + r0 + 4);
  float b2v[8] = {b2a.x,b2a.y,b2a.z,b2a.w, b2b.x,b2b.y,b2b.z,b2b.w};
  #pragma unroll
  for (int i=0;i<8;i++){
    float o[8];
    #pragma unroll
    for (int j=0;j<8;j++) o[j] = sigm(-(acc[i][j] + b2v[i]));   // 1 - sigmoid(y) == sigmoid(-y)
    float* dst = out + (size_t)(r0+i)*N_FRAMES + T0 + f0;
    *(float4*)(dst)     = make_float4(o[0],o[1],o[2],o[3]);
    *(float4*)(dst + 4) = make_float4(o[4],o[5],o[6],o[7]);
  }
}

extern "C" void kernel_launch(void* const* d_in, const int* in_sizes, int n_in,
                              void* d_out, int out_size, void* d_ws, size_t ws_size,
                              hipStream_t stream) {
  const float* x  = (const float*)d_in[0];   // (512, 65536)
  const float* W1 = (const float*)d_in[1];   // (256, 512)
  const float* B1 = (const float*)d_in[2];   // (256, 1)
  const float* W2 = (const float*)d_in[3];   // (256, 128)
  const float* B2 = (const float*)d_in[4];   // (256, 1)
  float* out = (float*)d_out;                // (256, 65536)

  float* ws  = (float*)d_ws;
  float* W1T = ws;                                   // 512*256
  float* W2T = W1T + (size_t)K1*M1;                  // 128*256
  float* Aa  = W2T + (size_t)MEM*M2;                 // 65536*128
  float* Bb  = Aa  + (size_t)N_FRAMES*MEM;           // 65536*128
  float* Ac  = Bb  + (size_t)N_FRAMES*MEM;           // 512*128
  float* Bc  = Ac  + (size_t)G*MEM;                  // 512*128
  float* Pb  = Bc  + (size_t)G*MEM;                  // 512*128

  k_prep <<<512, 256, 0, stream>>>(W1, W2, W1T, W2T);
  k_gemm1<<<N_FRAMES/TN, 256, 0, stream>>>(x, W1T, B1, Aa, Bb);
  k_red  <<<G, 128, 0, stream>>>(Aa, Bb, Ac, Bc);
  k_scan <<<1, 128, 0, stream>>>(Ac, Bc, Pb);
  k_apply<<<G, 512, 0, stream>>>(Aa, Bb, Pb, W2T, B2, out);
}

// Round 2
// 340.168 us; speedup vs baseline: 1.4713x; 1.4713x over previous
//
#include <hip/hip_runtime.h>

typedef unsigned short u16;
typedef short bf16x8 __attribute__((ext_vector_type(8)));
typedef float f32x4 __attribute__((ext_vector_type(4)));

#define NF 65536
#define GCH 512      // number of 128-frame chunks

__device__ __forceinline__ float sigm(float x){ return 1.0f/(1.0f+__expf(-x)); }

__device__ __forceinline__ u16 f2bf(float f){
  union { float f; unsigned u; } v; v.f = f;
  unsigned r = (v.u + 0x7fffu + ((v.u >> 16) & 1u)) >> 16;   // RNE
  return (u16)r;
}

#define AS1(p) ((const __attribute__((address_space(1))) unsigned int*)(p))
#define AS3(p) ((__attribute__((address_space(3))) unsigned int*)(p))

// ---------------- prep: pack W1, W2 into MFMA fragment-ready bf16 layouts.
// W1f: [ck 0..7][rt 0..15][ks 0..1][lane 0..63][j 0..7]
//   element = W1[16*rt + (lane&15)][ck*64 + ks*32 + (lane>>4)*8 + j]
// W2f: [rt 0..15][ks 0..3][lane 0..63][j 0..7]
//   element = W2[16*rt + (lane&15)][ks*32 + (lane>>4)*8 + j]
__global__ __launch_bounds__(256) void k_prep(const float* __restrict__ W1, const float* __restrict__ W2,
                                              u16* __restrict__ W1f, u16* __restrict__ W2f){
  int idx = blockIdx.x*256 + threadIdx.x;     // 0..131071
  {
    int j  = idx & 7;
    int L  = (idx >> 3) & 63;
    int ks = (idx >> 9) & 1;
    int rt = (idx >> 10) & 15;
    int ck = idx >> 14;
    int row = 16*rt + (L & 15);
    int k   = ck*64 + ks*32 + ((L >> 4) << 3) + j;
    W1f[idx] = f2bf(W1[row*512 + k]);
  }
  if (idx < 32768){
    int j  = idx & 7;
    int L  = (idx >> 3) & 63;
    int ks = (idx >> 9) & 3;
    int rt = idx >> 11;
    int row = 16*rt + (L & 15);
    int m   = ks*32 + ((L >> 4) << 3) + j;
    W2f[idx] = f2bf(W2[row*128 + m]);
  }
}

// ---------------- transpose+convert: x (512, 65536) fp32 -> xT (65536, 512) bf16
__global__ __launch_bounds__(256) void k_tr(const float* __restrict__ x, u16* __restrict__ xT){
  __shared__ float ls[64*65];                  // stride 65: 2-way max bank aliasing
  const int tid = threadIdx.x;
  const int bt = blockIdx.x & 1023, bk = blockIdx.x >> 10;   // 1024 x 8 tiles
  const int T0 = bt*64, K0 = bk*64;
  #pragma unroll
  for (int l=0;l<4;l++){
    int idx = tid + l*256;                     // 0..1023 float4s
    int kl = idx >> 4, c4 = idx & 15;
    float4 v = *(const float4*)(x + (size_t)(K0+kl)*NF + T0 + c4*4);
    float* d = ls + kl*65 + c4*4;
    d[0]=v.x; d[1]=v.y; d[2]=v.z; d[3]=v.w;
  }
  __syncthreads();
  #pragma unroll
  for (int l=0;l<2;l++){
    int p = tid + l*256;                       // 0..511 packs of 8
    int t = p >> 3, kb = p & 7;
    unsigned u[8];
    #pragma unroll
    for (int m=0;m<8;m++) u[m] = f2bf(ls[(kb*8+m)*65 + t]);
    uint4 pk;
    pk.x = u[0] | (u[1]<<16); pk.y = u[2] | (u[3]<<16);
    pk.z = u[4] | (u[5]<<16); pk.w = u[6] | (u[7]<<16);
    *(uint4*)(xT + (size_t)(T0+t)*512 + K0 + kb*8) = pk;
  }
}

// ---------------- GEMM1 (MFMA bf16): 256 rows x 128 frames per block, K=512
// wave wv owns row-tiles {2wv, 2wv+1, 2wv+8, 2wv+9} (rows 32wv..+31 and +128) x 8 col-tiles
__global__ __launch_bounds__(256, 2) void k_gemm1(const u16* __restrict__ xT,
        const u16* __restrict__ W1f, const float* __restrict__ B1,
        float* __restrict__ Aa, float* __restrict__ Bb){
  __shared__ __align__(16) u16 ws[16384];      // 32 KB: [rt][ks][lane][8]
  __shared__ __align__(16) u16 xs[8192];       // 16 KB: [c][ks][lane][8]
  const int tid = threadIdx.x;
  const int wv = tid >> 6, L = tid & 63;
  const int q = L >> 4, ln = L & 15;
  const int F0 = blockIdx.x * 128;
  const int rt0 = 2*wv;

  f32x4 acc[4][8];
  #pragma unroll
  for (int a=0;a<4;a++)
    #pragma unroll
    for (int c=0;c<8;c++) acc[a][c] = (f32x4){0.f,0.f,0.f,0.f};

  for (int ck=0; ck<8; ++ck){
    // stage W1f chunk: 32 KB contiguous, 32 instrs of 1 KB, 8 per wave
    #pragma unroll
    for (int i=0;i<8;i++){
      int s = wv*8 + i;
      __builtin_amdgcn_global_load_lds(AS1(W1f + ck*16384 + s*512 + L*8), AS3(ws + s*512), 16, 0, 0);
    }
    // stage x frags: 16 KB, 16 instrs, 4 per wave; per-lane gather from xT
    #pragma unroll
    for (int i=0;i<4;i++){
      int s = wv*4 + i;
      int c = s >> 1, ks = s & 1;
      int t = F0 + c*16 + ln;
      int k = ck*64 + ks*32 + q*8;
      __builtin_amdgcn_global_load_lds(AS1(xT + (size_t)t*512 + k), AS3(xs + s*512), 16, 0, 0);
    }
    __syncthreads();
    #pragma unroll
    for (int ks=0; ks<2; ++ks){
      bf16x8 af[4];
      af[0] = ((const bf16x8*)ws)[( rt0   *2+ks)*64 + L];
      af[1] = ((const bf16x8*)ws)[((rt0+1)*2+ks)*64 + L];
      af[2] = ((const bf16x8*)ws)[((rt0+8)*2+ks)*64 + L];
      af[3] = ((const bf16x8*)ws)[((rt0+9)*2+ks)*64 + L];
      #pragma unroll
      for (int c=0;c<8;c++){
        bf16x8 bf = ((const bf16x8*)xs)[(c*2+ks)*64 + L];
        acc[0][c] = __builtin_amdgcn_mfma_f32_16x16x32_bf16(af[0], bf, acc[0][c], 0,0,0);
        acc[1][c] = __builtin_amdgcn_mfma_f32_16x16x32_bf16(af[1], bf, acc[1][c], 0,0,0);
        acc[2][c] = __builtin_amdgcn_mfma_f32_16x16x32_bf16(af[2], bf, acc[2][c], 0,0,0);
        acc[3][c] = __builtin_amdgcn_mfma_f32_16x16x32_bf16(af[3], bf, acc[3][c], 0,0,0);
      }
    }
    __syncthreads();
  }
  // epilogue: sigmoid, a = le*ri, b = 1-le; rs pairs (0,2) and (1,3) are rows m, m+128
  #pragma unroll
  for (int pr=0; pr<2; ++pr){
    int mb = 32*wv + 16*pr + 4*q;              // row base in 0..124
    float bl[4], br[4];
    #pragma unroll
    for (int r=0;r<4;r++){ bl[r] = B1[mb+r]; br[r] = B1[mb+128+r]; }
    #pragma unroll
    for (int c=0;c<8;c++){
      int t = F0 + 16*c + ln;
      f32x4 Lv = acc[pr][c], Rv = acc[pr+2][c];
      float a4[4], b4[4];
      #pragma unroll
      for (int r=0;r<4;r++){
        float le = sigm(Lv[r] + bl[r]);
        float ri = sigm(Rv[r] + br[r]);
        a4[r] = le*ri; b4[r] = 1.0f - le;
      }
      *(float4*)(Aa + (size_t)t*128 + mb) = make_float4(a4[0],a4[1],a4[2],a4[3]);
      *(float4*)(Bb + (size_t)t*128 + mb) = make_float4(b4[0],b4[1],b4[2],b4[3]);
    }
  }
}

// ---------------- chunk-local affine composition (fp32, unchanged)
__global__ __launch_bounds__(128) void k_red(const float* __restrict__ Aa, const float* __restrict__ Bb,
                                             float* __restrict__ Ac, float* __restrict__ Bc){
  const int m = threadIdx.x, g = blockIdx.x;
  const float* ap = Aa + (size_t)g*128*128 + m;
  const float* bp = Bb + (size_t)g*128*128 + m;
  float A = 1.f, B = 0.f;
  #pragma unroll 8
  for (int t=0;t<128;t++){
    float a = ap[(size_t)t*128], b = bp[(size_t)t*128];
    B = fmaf(a, B, b);
    A *= a;
  }
  Ac[g*128+m] = A;
  Bc[g*128+m] = B;
}

__global__ __launch_bounds__(128) void k_scan(const float* __restrict__ Ac, const float* __restrict__ Bc,
                                              float* __restrict__ Pb){
  const int m = threadIdx.x;
  float B = 0.f;
  #pragma unroll 8
  for (int g=0; g<GCH; ++g){
    Pb[g*128+m] = B;
    B = fmaf(Ac[g*128+m], B, Bc[g*128+m]);
  }
}

// ---------------- apply: recompute z (bf16, straight into B-frag layout) + MFMA GEMM2 + epilogue
// zf: [c 0..7][ks 0..3][lane 0..63][j 0..7]; element (m,t): c=t>>4, ks=m>>5,
//     lane=((m>>3)&3)*16 + (t&15), j=m&7
__global__ __launch_bounds__(512, 2) void k_apply(const float* __restrict__ Aa, const float* __restrict__ Bb,
        const float* __restrict__ Pb, const u16* __restrict__ W2f, const float* __restrict__ B2,
        float* __restrict__ out){
  __shared__ __align__(16) u16 zf[16384];      // 32 KB
  const int tid = threadIdx.x;
  const int g = blockIdx.x, T0 = g*128;

  if (tid < 128){
    const int m = tid;
    float s = Pb[g*128 + m];
    const float* ap = Aa + (size_t)T0*128 + m;
    const float* bp = Bb + (size_t)T0*128 + m;
    const int base_m = (m>>5)*512 + ((m>>3)&3)*128 + (m&7);
    #pragma unroll 4
    for (int t=0;t<128;t++){
      zf[base_m + (t>>4)*2048 + (t&15)*8] = f2bf(s);
      s = fmaf(ap[(size_t)t*128], s, bp[(size_t)t*128]);
    }
  }
  __syncthreads();

  const int wv = tid >> 6, L = tid & 63;
  const int q = L >> 4, ln = L & 15;
  f32x4 acc[2][8];
  #pragma unroll
  for (int a=0;a<2;a++)
    #pragma unroll
    for (int c=0;c<8;c++) acc[a][c] = (f32x4){0.f,0.f,0.f,0.f};

  #pragma unroll
  for (int ks=0; ks<4; ++ks){
    bf16x8 af0 = ((const bf16x8*)W2f)[((2*wv  )*4+ks)*64 + L];   // L2-hot, 64 KB
    bf16x8 af1 = ((const bf16x8*)W2f)[((2*wv+1)*4+ks)*64 + L];
    #pragma unroll
    for (int c=0;c<8;c++){
      bf16x8 bf = ((const bf16x8*)zf)[(c*4+ks)*64 + L];
      acc[0][c] = __builtin_amdgcn_mfma_f32_16x16x32_bf16(af0, bf, acc[0][c], 0,0,0);
      acc[1][c] = __builtin_amdgcn_mfma_f32_16x16x32_bf16(af1, bf, acc[1][c], 0,0,0);
    }
  }

  #pragma unroll
  for (int rs=0;rs<2;rs++){
    int rowb = (2*wv+rs)*16 + q*4;
    float b2[4];
    #pragma unroll
    for (int r=0;r<4;r++) b2[r] = B2[rowb+r];
    #pragma unroll
    for (int c=0;c<8;c++){
      int t = T0 + 16*c + ln;
      #pragma unroll
      for (int r=0;r<4;r++)
        out[(size_t)(rowb+r)*NF + t] = sigm(-(acc[rs][c][r] + b2[r]));  // 1-sigmoid(y)=sigmoid(-y)
    }
  }
}

extern "C" void kernel_launch(void* const* d_in, const int* in_sizes, int n_in,
                              void* d_out, int out_size, void* d_ws, size_t ws_size,
                              hipStream_t stream) {
  const float* x  = (const float*)d_in[0];   // (512, 65536)
  const float* W1 = (const float*)d_in[1];   // (256, 512)
  const float* B1 = (const float*)d_in[2];   // (256, 1)
  const float* W2 = (const float*)d_in[3];   // (256, 128)
  const float* B2 = (const float*)d_in[4];   // (256, 1)
  float* out = (float*)d_out;                // (256, 65536) = 64 MB

  u16*   W1f = (u16*)d_ws;                   // 131072 u16
  u16*   W2f = W1f + 131072;                 // 32768 u16
  float* Aa  = (float*)d_ws + 81920;         // 65536*128 fp32
  float* Bb  = Aa + (size_t)NF*128;
  float* Ac  = Bb + (size_t)NF*128;
  float* Bc  = Ac + (size_t)GCH*128;
  float* Pb  = Bc + (size_t)GCH*128;
  u16*   xT  = (u16*)d_out;                  // 64 MB, dead before k_apply writes out

  k_prep <<<512, 256, 0, stream>>>(W1, W2, W1f, W2f);
  k_tr   <<<8192, 256, 0, stream>>>(x, xT);
  k_gemm1<<<512, 256, 0, stream>>>(xT, W1f, B1, Aa, Bb);
  k_red  <<<GCH, 128, 0, stream>>>(Aa, Bb, Ac, Bc);
  k_scan <<<1, 128, 0, stream>>>(Ac, Bc, Pb);
  k_apply<<<GCH, 512, 0, stream>>>(Aa, Bb, Pb, W2f, B2, out);
}